// Round 6
// baseline (193.164 us; speedup 1.0000x reference)
//
#include <hip/hip_runtime.h>

#define NBINS 256
#define TILE  128          // tile is 128x128 -> 16384 pixels
#define CLIPV 2560u        // max(40 * 16384 // 256, 1)

typedef float fx4 __attribute__((ext_vector_type(4)));   // native vec for nontemporal ops

// ws layout: [0, 384K) u8 LUT, 1536 tiles x 256 bins. No idx plane: apply
// re-reads x, which is L3-resident after hist's (cache-allocating) pass.

// ---------------------------------------------------------------------------
// Kernel 1: per-tile histogram -> clip -> redistribute -> cumsum -> u8 LUT.
// One block per tile (1536), 256 threads (4 waves).
// 8-way bin-major sub-histograms: hs[bin*8 + (tid&7)]; random bins spread
// ~2 lanes/bank (free per m136) and same-address atomic serialization is rare.
// x loads are NORMAL (not nontemporal) so x allocates in L3 for kernel 2.
// ---------------------------------------------------------------------------
__global__ __launch_bounds__(256) void clahe_hist_lut(
        const float* __restrict__ x, unsigned char* __restrict__ lut8) {
    const int t   = blockIdx.x;          // tile id: ((b*3+c)*8+ty)*8+tx
    const int tid = threadIdx.x;

    __shared__ unsigned int hs[NBINS * 8];   // bin-major interleaved
    __shared__ int          scan[2][NBINS];
    __shared__ unsigned int wsum[4];

    #pragma unroll
    for (int k = 0; k < 8; ++k) hs[k * NBINS + tid] = 0u;
    __syncthreads();

    const int tx = t & 7;
    const int ty = (t >> 3) & 7;
    const int bc = t >> 6;
    const float* base = x + ((size_t)bc * 1024 + (size_t)ty * TILE) * 1024
                          + (size_t)tx * TILE;

    const int sub    = tid & 7;
    const int lane32 = tid & 31;   // float4 column within the tile row
    const int rgrp   = tid >> 5;   // 0..7 -> 8 rows covered per iteration
    #pragma unroll 4
    for (int rr = 0; rr < 16; ++rr) {
        const int row = rr * 8 + rgrp;
        const fx4 v = *(const fx4*)(base + (size_t)row * 1024 + lane32 * 4);
        const int b0 = min(max((int)(v.x * 256.0f), 0), 255);
        const int b1 = min(max((int)(v.y * 256.0f), 0), 255);
        const int b2 = min(max((int)(v.z * 256.0f), 0), 255);
        const int b3 = min(max((int)(v.w * 256.0f), 0), 255);
        atomicAdd(&hs[b0 * 8 + sub], 1u);
        atomicAdd(&hs[b1 * 8 + sub], 1u);
        atomicAdd(&hs[b2 * 8 + sub], 1u);
        atomicAdd(&hs[b3 * 8 + sub], 1u);
    }
    __syncthreads();

    // gather the 8 sub-counts for bin `tid`
    const uint4* hp = (const uint4*)(&hs[tid * 8]);
    const uint4 ha = hp[0], hb = hp[1];
    const unsigned int total = ha.x + ha.y + ha.z + ha.w
                             + hb.x + hb.y + hb.z + hb.w;
    const unsigned int hv = min(total, CLIPV);
    unsigned int e = total - hv;               // excess clipped from this bin
    #pragma unroll
    for (int off = 32; off > 0; off >>= 1) e += __shfl_down(e, off, 64);
    if ((tid & 63) == 0) wsum[tid >> 6] = e;
    __syncthreads();
    const unsigned int E        = wsum[0] + wsum[1] + wsum[2] + wsum[3];
    const unsigned int add      = E >> 8;      // (clipped - residual)/256
    const unsigned int residual = E & 255u;    // clipped mod 256
    const int h2 = (int)(hv + add + ((unsigned)tid < residual ? 1u : 0u));

    // inclusive scan over 256 bins (Hillis-Steele, ping-pong)
    scan[0][tid] = h2;
    __syncthreads();
    int src = 0;
    #pragma unroll
    for (int off = 1; off < 256; off <<= 1) {
        int v = scan[src][tid];
        if (tid >= off) v += scan[src][tid - off];
        scan[src ^ 1][tid] = v;
        __syncthreads();
        src ^= 1;
    }
    const int cum = scan[src][tid];
    // 255/16384 = 255 * 2^-14: fp32 multiply is exact here (cum*255 < 2^22)
    // result is an exact integer 0..255 -> u8
    const float l = fminf((float)cum * (255.0f / 16384.0f), 255.0f);
    lut8[(size_t)t * NBINS + tid] = (unsigned char)floorf(l);
}

// ---------------------------------------------------------------------------
// Kernel 2: bilinear LUT interpolation, reading x again (L3-hot).
// One block per (bc, 16-row group); (r0,r1) uniform over the group.
// LDS pair-table: ptab[c0*256+i] packs {l_r0[c0][i], l_r0[c1][i],
// l_r1[c0][i], l_r1[c1][i]} as 4 u8 in one u32 -> all four bilinear taps are
// a single ds_read_b32 per pixel. wx=1 / wy=1 edges remain exact because the
// factored blend g01 + 1.0*(g00-g01) is exact for small integers.
// x loads nontemporal-read (hits L3, no re-allocation churn); out stores
// nontemporal so the output stream does not evict x from L3.
// ---------------------------------------------------------------------------
__global__ __launch_bounds__(256) void clahe_apply(
        const float* __restrict__ x,
        const unsigned char* __restrict__ lut8,
        float* __restrict__ out) {
    __shared__ unsigned int ptab[8 * NBINS];

    const int blk = blockIdx.x;
    const int bc  = blk >> 6;          // 64 16-row groups per image plane
    const int rg  = blk & 63;
    const int y0  = rg * 16;
    const int tid = threadIdx.x;

    // row-axis interpolation coords (half = 64, denom = 127) — group-uniform
    const int j = y0 >> 6;
    int r0 = (j - 1) >> 1;             // matches Python floor division
    r0 = min(max(r0, 0), 7);
    const int r1 = min(r0 + 1, 7);

    // build the pair table: 16 coalesced byte loads + 8 LDS stores per thread
    {
        const unsigned char* L0 = lut8 + (size_t)bc * 64 * NBINS + (size_t)r0 * 8 * NBINS;
        const unsigned char* L1 = lut8 + (size_t)bc * 64 * NBINS + (size_t)r1 * 8 * NBINS;
        unsigned a0[8], a1[8];
        #pragma unroll
        for (int c = 0; c < 8; ++c) {
            a0[c] = L0[c * NBINS + tid];
            a1[c] = L1[c * NBINS + tid];
        }
        #pragma unroll
        for (int c0 = 0; c0 < 8; ++c0) {
            const int c1 = min(c0 + 1, 7);
            ptab[c0 * NBINS + tid] =
                a0[c0] | (a0[c1] << 8) | (a1[c0] << 16) | (a1[c1] << 24);
        }
    }
    __syncthreads();

    // column-axis params for this thread's 4 columns (fixed across rows)
    int ock[4];
    float wxk[4];
    #pragma unroll
    for (int k = 0; k < 4; ++k) {
        const int xx = tid * 4 + k;
        const int jc = xx >> 6, pc = xx & 63;
        int c0 = (jc - 1) >> 1;
        c0 = min(max(c0, 0), 7);
        ock[k] = c0 * NBINS;
        wxk[k] = (jc == 0) ? 1.0f
               : (float)((jc & 1) ? (127 - pc) : (63 - pc)) / 127.0f;
    }

    const bool jzero = (j == 0);
    const bool jodd  = (j & 1);
    const size_t rowbase = ((size_t)bc * 1024 + (size_t)y0) * 1024 + tid * 4;

    #pragma unroll 4
    for (int r = 0; r < 16; ++r) {
        const int p = (y0 + r) & 63;
        const float wy = jzero ? 1.0f
                       : (float)(jodd ? (127 - p) : (63 - p)) / 127.0f;

        const fx4 v = __builtin_nontemporal_load(
            (const fx4*)(x + rowbase + (size_t)r * 1024));
        const float vv[4] = {v.x, v.y, v.z, v.w};
        float res[4];
        #pragma unroll
        for (int k = 0; k < 4; ++k) {
            const unsigned id = (unsigned)min(max((int)(vv[k] * 255.0f), 0), 255);
            const unsigned e = ptab[ock[k] + id];
            const float g00 = (float)(e & 0xffu);
            const float g01 = (float)((e >> 8) & 0xffu);
            const float g10 = (float)((e >> 16) & 0xffu);
            const float g11 = (float)(e >> 24);
            const float wx = wxk[k];
            const float a = fmaf(wx, g00 - g01, g01);  // row r0 interp
            const float b = fmaf(wx, g10 - g11, g11);  // row r1 interp
            res[k] = fmaf(wy, a - b, b) * (1.0f / 255.0f);
        }
        const fx4 o4 = {res[0], res[1], res[2], res[3]};
        __builtin_nontemporal_store(
            o4, (fx4*)(out + rowbase + (size_t)r * 1024));
    }
}

extern "C" void kernel_launch(void* const* d_in, const int* in_sizes, int n_in,
                              void* d_out, int out_size, void* d_ws, size_t ws_size,
                              hipStream_t stream) {
    const float* x = (const float*)d_in[0];
    float* out = (float*)d_out;
    unsigned char* lut8 = (unsigned char*)d_ws;   // 384 KB

    clahe_hist_lut<<<1536, 256, 0, stream>>>(x, lut8);
    // 24 planes * 64 sixteen-row groups = 1536 blocks
    clahe_apply<<<24 * 64, 256, 0, stream>>>(x, lut8, out);
}